// Round 21
// baseline (51.096 us; speedup 1.0000x reference)
//
#include <hip/hip_runtime.h>
#include <math.h>

#define B_  2048
#define T_  200
#define D_  64
#define H1_ 80
#define H2_ 40

#define WSTR 104   // ws W2T row stride (bf16)
#define NLOG2E (-1.4426950408889634f)
#define LOG2E  (1.4426950408889634f)

// d_ws layout (bytes):
#define WS_A    0        // A[h][f]  bf16 [80][64]   (pre-scaled by -log2e)
#define WS_C    10240    // C[h][f]  bf16 [80][64]   (pre-scaled by -log2e)
#define WS_W2T  20480    // W2Tp[g][h] bf16 [48][104] (pre-scaled by -log2e)
#define WS_ACT  30464    // W1acT[h][f] f32 [80][64]  (unscaled)

typedef __bf16 bf16x8 __attribute__((ext_vector_type(8)));
typedef float  f32x4  __attribute__((ext_vector_type(4)));

// y is already -log2e * x : sigmoid(x) = 1 / (1 + 2^y)
__device__ __forceinline__ float sigmoid2_(float y) {
    return __builtin_amdgcn_rcpf(1.0f + __builtin_amdgcn_exp2f(y));
}
__device__ __forceinline__ unsigned pk2_(float a, float b) {
    __bf16 x = (__bf16)a, y = (__bf16)b;
    unsigned short ux = __builtin_bit_cast(unsigned short, x);
    unsigned short uy = __builtin_bit_cast(unsigned short, y);
    return (unsigned)ux | ((unsigned)uy << 16);
}

// ---------- prep: block-invariant weight transforms (exp2-folded) ----------
__global__ __launch_bounds__(256)
void prep_kernel(const float* __restrict__ W1, const float* __restrict__ W2,
                 void* __restrict__ ws)
{
    __bf16* A    = (__bf16*)((char*)ws + WS_A);
    __bf16* C    = (__bf16*)((char*)ws + WS_C);
    __bf16* W2Tp = (__bf16*)((char*)ws + WS_W2T);
    float*  acT  = (float*)((char*)ws + WS_ACT);
    const int e0 = blockIdx.x * 256 + threadIdx.x;

    for (int e = e0; e < H1_ * D_; e += 2048) {
        int h = e >> 6, f = e & 63;
        float wb = W1[(64  + f) * H1_ + h];
        float wc = W1[(128 + f) * H1_ + h];
        float wd = W1[(192 + f) * H1_ + h];
        float wa = W1[f * H1_ + h];
        A[e]   = (__bf16)(NLOG2E * (wb - wc));
        C[e]   = (__bf16)(NLOG2E * wd);
        acT[e] = wa + wc;
    }
    for (int e = e0; e < 48 * WSTR; e += 2048) {
        int g = e / WSTR, h = e - g * WSTR;
        W2Tp[e] = (g < H2_ && h < H1_) ? (__bf16)(NLOG2E * W2[h * H2_ + g]) : (__bf16)0.0f;
    }
}

// ---------- main: 2 batches/block, each split over a wave pair (parity); fixed-m merge ----------
__global__ __launch_bounds__(256, 2)
void attn_din21(const float* __restrict__ query,
                const float* __restrict__ key,
                const int*   __restrict__ mask,
                const float* __restrict__ b1,
                const float* __restrict__ b2,
                const float* __restrict__ W3,
                const float* __restrict__ b3,
                const void*  __restrict__ ws,
                float* __restrict__ out)
{
    __shared__ __align__(16) float s_q[2][D_];
    __shared__ float s_base[2][H1_];
    __shared__ float s_part[4][D_];
    __shared__ float s_l[4];
    // ~2.8 KB

    const int tid  = threadIdx.x;
    const int lane = tid & 63;
    const int w    = tid >> 6;          // wave 0..3
    const int bs   = w >> 1;            // batch slot 0/1
    const int wp   = w & 1;             // parity within batch
    const int c16  = lane & 15;
    const int g16  = lane >> 4;
    const int b    = blockIdx.x * 2 + bs;

    const int   mv     = mask[b];
    const int   npairs = (mv + 31) >> 5;
    const float b3s    = b3[0] * 0.125f * LOG2E;
    const float* kb = key + (size_t)b * T_ * D_;

    const __bf16* wsA   = (const __bf16*)((const char*)ws + WS_A);
    const __bf16* wsC   = (const __bf16*)((const char*)ws + WS_C);
    const __bf16* wsW2T = (const __bf16*)((const char*)ws + WS_W2T);
    const float*  wsacT = (const float*) ((const char*)ws + WS_ACT);

    // ---- q + first own pair's key loads issued early (rows wp*32 + c16 / +16, all <200) ----
    float qv = query[b * D_ + lane];
    float4 uA0, uA1, uA2, uA3, uB0, uB1, uB2, uB3;
    {
        const float* krA = kb + (size_t)(wp * 32 + c16) * D_ + g16 * 8;
        const float* krB = kb + (size_t)(wp * 32 + 16 + c16) * D_ + g16 * 8;
        uA0 = *(const float4*)(krA);      uA1 = *(const float4*)(krA + 4);
        uA2 = *(const float4*)(krA + 32); uA3 = *(const float4*)(krA + 36);
        uB0 = *(const float4*)(krB);      uB1 = *(const float4*)(krB + 4);
        uB2 = *(const float4*)(krB + 32); uB3 = *(const float4*)(krB + 36);
    }
    s_q[bs][lane] = qv;   // both waves of the pair write identical values (benign)

    // ---- W2T A-fragments (pre-scaled by -log2e) ----
    bf16x8 bw[3][3];
    #pragma unroll
    for (int nt = 0; nt < 3; ++nt)
        #pragma unroll
        for (int ks = 0; ks < 3; ++ks)
            bw[nt][ks] = *(const bf16x8*)&wsW2T[(nt * 16 + c16) * WSTR + ks * 32 + g16 * 8];

    // ---- per-lane bias/weight rows ----
    float b2c[3][4], w3c[3][4];
    #pragma unroll
    for (int nt = 0; nt < 3; ++nt)
        #pragma unroll
        for (int r = 0; r < 4; ++r) {
            int g = nt * 16 + g16 * 4 + r;
            b2c[nt][r] = (g < H2_) ? b2[g] * NLOG2E : 0.0f;
            w3c[nt][r] = (g < H2_) ? W3[g] * 0.125f * LOG2E : 0.0f;
        }

    // ---- base[h] (computed identically by both waves of the pair) ----
    {
        float a0 = b1[lane], a1 = 0.0f, a2 = 0.0f, a3 = 0.0f;
        const f32x4* row = (const f32x4*)&wsacT[lane * D_];
        #pragma unroll
        for (int f4 = 0; f4 < 16; ++f4) {
            f32x4 v  = row[f4];
            f32x4 q4 = *(const f32x4*)&s_q[bs][f4 * 4];
            a0 = fmaf(q4[0], v[0], a0);
            a1 = fmaf(q4[1], v[1], a1);
            a2 = fmaf(q4[2], v[2], a2);
            a3 = fmaf(q4[3], v[3], a3);
        }
        s_base[bs][lane] = (a0 + a1) + (a2 + a3);
    }
    if (lane < 16) {
        int h = 64 + lane;
        float a0 = b1[h], a1 = 0.0f, a2 = 0.0f, a3 = 0.0f;
        const f32x4* row = (const f32x4*)&wsacT[h * D_];
        #pragma unroll
        for (int f4 = 0; f4 < 16; ++f4) {
            f32x4 v  = row[f4];
            f32x4 q4 = *(const f32x4*)&s_q[bs][f4 * 4];
            a0 = fmaf(q4[0], v[0], a0);
            a1 = fmaf(q4[1], v[1], a1);
            a2 = fmaf(q4[2], v[2], a2);
            a3 = fmaf(q4[3], v[3], a3);
        }
        s_base[bs][h] = (a0 + a1) + (a2 + a3);
    }

    // ---- V A-fragments (pre-scaled) ----
    bf16x8 bv[5][2];
    #pragma unroll
    for (int mt = 0; mt < 5; ++mt)
        #pragma unroll
        for (int ks = 0; ks < 2; ++ks) {
            int off = (mt * 16 + c16) * D_ + ks * 32 + g16 * 8;
            bf16x8 a8 = *(const bf16x8*)&wsA[off];
            bf16x8 c8 = *(const bf16x8*)&wsC[off];
            f32x4 q0 = *(const f32x4*)&s_q[bs][ks * 32 + g16 * 8];
            f32x4 q1 = *(const f32x4*)&s_q[bs][ks * 32 + g16 * 8 + 4];
            bf16x8 v8;
            v8[0] = (__bf16)((float)a8[0] + q0[0] * (float)c8[0]);
            v8[1] = (__bf16)((float)a8[1] + q0[1] * (float)c8[1]);
            v8[2] = (__bf16)((float)a8[2] + q0[2] * (float)c8[2]);
            v8[3] = (__bf16)((float)a8[3] + q0[3] * (float)c8[3]);
            v8[4] = (__bf16)((float)a8[4] + q1[0] * (float)c8[4]);
            v8[5] = (__bf16)((float)a8[5] + q1[1] * (float)c8[5]);
            v8[6] = (__bf16)((float)a8[6] + q1[2] * (float)c8[6]);
            v8[7] = (__bf16)((float)a8[7] + q1[3] * (float)c8[7]);
            bv[mt][ks] = v8;
        }

    // ---- per-lane base rows, scaled by -log2e ----
    float base_c[5][4];
    #pragma unroll
    for (int mt = 0; mt < 5; ++mt)
        #pragma unroll
        for (int r = 0; r < 4; ++r)
            base_c[mt][r] = s_base[bs][16 * mt + g16 * 4 + r] * NLOG2E;

    // ---- shfl-assembly constants ----
    const int  L0 = ((g16 & 1) << 5) + c16;
    const int  L1 = L0 + 16;
    const bool hi = (g16 >= 2);

    // ---- accumulators ----
    float o00,o01,o02,o03,o04,o05,o06,o07,o08,o09,o10,o11,o12,o13,o14,o15;
    o00=o01=o02=o03=o04=o05=o06=o07=o08=o09=o10=o11=o12=o13=o14=o15=0.0f;
    float l_run = 0.0f;

    // ---------------- main loop: own-parity pairs ----------------
    for (int pp = wp; pp < npairs; pp += 2) {
        bf16x8 afA0, afA1, afB0, afB1;
        afA0[0]=(__bf16)uA0.x; afA0[1]=(__bf16)uA0.y; afA0[2]=(__bf16)uA0.z; afA0[3]=(__bf16)uA0.w;
        afA0[4]=(__bf16)uA1.x; afA0[5]=(__bf16)uA1.y; afA0[6]=(__bf16)uA1.z; afA0[7]=(__bf16)uA1.w;
        afA1[0]=(__bf16)uA2.x; afA1[1]=(__bf16)uA2.y; afA1[2]=(__bf16)uA2.z; afA1[3]=(__bf16)uA2.w;
        afA1[4]=(__bf16)uA3.x; afA1[5]=(__bf16)uA3.y; afA1[6]=(__bf16)uA3.z; afA1[7]=(__bf16)uA3.w;
        afB0[0]=(__bf16)uB0.x; afB0[1]=(__bf16)uB0.y; afB0[2]=(__bf16)uB0.z; afB0[3]=(__bf16)uB0.w;
        afB0[4]=(__bf16)uB1.x; afB0[5]=(__bf16)uB1.y; afB0[6]=(__bf16)uB1.z; afB0[7]=(__bf16)uB1.w;
        afB1[0]=(__bf16)uB2.x; afB1[1]=(__bf16)uB2.y; afB1[2]=(__bf16)uB2.z; afB1[3]=(__bf16)uB2.w;
        afB1[4]=(__bf16)uB3.x; afB1[5]=(__bf16)uB3.y; afB1[6]=(__bf16)uB3.z; afB1[7]=(__bf16)uB3.w;

        // T14 prefetch next own-parity pair
        if (pp + 2 < npairs) {
            int trA = (pp + 2) * 32 + c16;
            int trB = trA + 16;
            const float* krA = kb + (size_t)((trA < T_) ? trA : (T_ - 1)) * D_ + g16 * 8;
            const float* krB = kb + (size_t)((trB < T_) ? trB : (T_ - 1)) * D_ + g16 * 8;
            uA0 = *(const float4*)(krA);      uA1 = *(const float4*)(krA + 4);
            uA2 = *(const float4*)(krA + 32); uA3 = *(const float4*)(krA + 36);
            uB0 = *(const float4*)(krB);      uB1 = *(const float4*)(krB + 4);
            uB2 = *(const float4*)(krB + 32); uB3 = *(const float4*)(krB + 36);
        }

        // layer 1 swapped; sigmoid via exp2 -> packed bf16
        unsigned pkA[5][2], pkB[5][2];
        __builtin_amdgcn_s_setprio(1);
        #pragma unroll
        for (int mt = 0; mt < 5; ++mt) {
            f32x4 cA = { base_c[mt][0], base_c[mt][1], base_c[mt][2], base_c[mt][3] };
            cA = __builtin_amdgcn_mfma_f32_16x16x32_bf16(bv[mt][0], afA0, cA, 0, 0, 0);
            cA = __builtin_amdgcn_mfma_f32_16x16x32_bf16(bv[mt][1], afA1, cA, 0, 0, 0);
            f32x4 cB = { base_c[mt][0], base_c[mt][1], base_c[mt][2], base_c[mt][3] };
            cB = __builtin_amdgcn_mfma_f32_16x16x32_bf16(bv[mt][0], afB0, cB, 0, 0, 0);
            cB = __builtin_amdgcn_mfma_f32_16x16x32_bf16(bv[mt][1], afB1, cB, 0, 0, 0);
            pkA[mt][0] = pk2_(sigmoid2_(cA[0]), sigmoid2_(cA[1]));
            pkA[mt][1] = pk2_(sigmoid2_(cA[2]), sigmoid2_(cA[3]));
            pkB[mt][0] = pk2_(sigmoid2_(cB[0]), sigmoid2_(cB[1]));
            pkB[mt][1] = pk2_(sigmoid2_(cB[2]), sigmoid2_(cB[3]));
        }
        __builtin_amdgcn_s_setprio(0);

        // B-frag assembly + layer 2 + layer 3, per sub-tile
        float sA, sB;
        #pragma unroll
        for (int sub = 0; sub < 2; ++sub) {
            unsigned w00,w01,w02,w03, w10,w11,w12,w13, w20,w21,w22,w23;
            {
                #define PKX(m,i) (sub ? pkB[m][i] : pkA[m][i])
                unsigned a,bq;
                a = __shfl(PKX(0,0), L0); bq = __shfl(PKX(1,0), L0); w00 = hi ? bq : a;
                a = __shfl(PKX(0,1), L0); bq = __shfl(PKX(1,1), L0); w01 = hi ? bq : a;
                a = __shfl(PKX(0,0), L1); bq = __shfl(PKX(1,0), L1); w02 = hi ? bq : a;
                a = __shfl(PKX(0,1), L1); bq = __shfl(PKX(1,1), L1); w03 = hi ? bq : a;
                a = __shfl(PKX(2,0), L0); bq = __shfl(PKX(3,0), L0); w10 = hi ? bq : a;
                a = __shfl(PKX(2,1), L0); bq = __shfl(PKX(3,1), L0); w11 = hi ? bq : a;
                a = __shfl(PKX(2,0), L1); bq = __shfl(PKX(3,0), L1); w12 = hi ? bq : a;
                a = __shfl(PKX(2,1), L1); bq = __shfl(PKX(3,1), L1); w13 = hi ? bq : a;
                a = __shfl(PKX(4,0), L0);                            w20 = hi ? 0u : a;
                a = __shfl(PKX(4,1), L0);                            w21 = hi ? 0u : a;
                a = __shfl(PKX(4,0), L1);                            w22 = hi ? 0u : a;
                a = __shfl(PKX(4,1), L1);                            w23 = hi ? 0u : a;
                #undef PKX
            }
            union { unsigned u[4]; bf16x8 v; } cv0, cv1, cv2;
            cv0.u[0]=w00; cv0.u[1]=w01; cv0.u[2]=w02; cv0.u[3]=w03;
            cv1.u[0]=w10; cv1.u[1]=w11; cv1.u[2]=w12; cv1.u[3]=w13;
            cv2.u[0]=w20; cv2.u[1]=w21; cv2.u[2]=w22; cv2.u[3]=w23;

            float p0 = 0.0f, p1 = 0.0f, p2 = 0.0f, p3 = 0.0f;
            __builtin_amdgcn_s_setprio(1);
            #pragma unroll
            for (int nt2 = 0; nt2 < 3; ++nt2) {
                f32x4 c = { b2c[nt2][0], b2c[nt2][1], b2c[nt2][2], b2c[nt2][3] };
                c = __builtin_amdgcn_mfma_f32_16x16x32_bf16(bw[nt2][0], cv0.v, c, 0, 0, 0);
                c = __builtin_amdgcn_mfma_f32_16x16x32_bf16(bw[nt2][1], cv1.v, c, 0, 0, 0);
                c = __builtin_amdgcn_mfma_f32_16x16x32_bf16(bw[nt2][2], cv2.v, c, 0, 0, 0);
                p0 = fmaf(sigmoid2_(c[0]), w3c[nt2][0], p0);
                p1 = fmaf(sigmoid2_(c[1]), w3c[nt2][1], p1);
                p2 = fmaf(sigmoid2_(c[2]), w3c[nt2][2], p2);
                p3 = fmaf(sigmoid2_(c[3]), w3c[nt2][3], p3);
            }
            __builtin_amdgcn_s_setprio(0);
            float partial = (p0 + p1) + (p2 + p3);
            partial += __shfl_xor(partial, 16);
            partial += __shfl_xor(partial, 32);
            float sc = partial + b3s;
            if (sub == 0) sA = sc; else sB = sc;
        }

        // fixed-m softmax in exp2 domain
        const int tb = pp * 32;
        float pA = (tb + c16 < mv)      ? __builtin_amdgcn_exp2f(sA) : 0.0f;
        float pB = (tb + 16 + c16 < mv) ? __builtin_amdgcn_exp2f(sB) : 0.0f;
        l_run += pA + pB;

        o00 = fmaf(pB, (float)afB0[0], fmaf(pA, (float)afA0[0], o00));
        o01 = fmaf(pB, (float)afB0[1], fmaf(pA, (float)afA0[1], o01));
        o02 = fmaf(pB, (float)afB0[2], fmaf(pA, (float)afA0[2], o02));
        o03 = fmaf(pB, (float)afB0[3], fmaf(pA, (float)afA0[3], o03));
        o04 = fmaf(pB, (float)afB0[4], fmaf(pA, (float)afA0[4], o04));
        o05 = fmaf(pB, (float)afB0[5], fmaf(pA, (float)afA0[5], o05));
        o06 = fmaf(pB, (float)afB0[6], fmaf(pA, (float)afA0[6], o06));
        o07 = fmaf(pB, (float)afB0[7], fmaf(pA, (float)afA0[7], o07));
        o08 = fmaf(pB, (float)afB1[0], fmaf(pA, (float)afA1[0], o08));
        o09 = fmaf(pB, (float)afB1[1], fmaf(pA, (float)afA1[1], o09));
        o10 = fmaf(pB, (float)afB1[2], fmaf(pA, (float)afA1[2], o10));
        o11 = fmaf(pB, (float)afB1[3], fmaf(pA, (float)afA1[3], o11));
        o12 = fmaf(pB, (float)afB1[4], fmaf(pA, (float)afA1[4], o12));
        o13 = fmaf(pB, (float)afB1[5], fmaf(pA, (float)afA1[5], o13));
        o14 = fmaf(pB, (float)afB1[6], fmaf(pA, (float)afA1[6], o14));
        o15 = fmaf(pB, (float)afB1[7], fmaf(pA, (float)afA1[7], o15));
    }

    // ---------------- per-wave reduce, then fixed-m additive merge across wave pair ----------------
    #define ORED(X) X += __shfl_xor(X,1); X += __shfl_xor(X,2); X += __shfl_xor(X,4); X += __shfl_xor(X,8);
    ORED(o00) ORED(o01) ORED(o02) ORED(o03) ORED(o04) ORED(o05) ORED(o06) ORED(o07)
    ORED(o08) ORED(o09) ORED(o10) ORED(o11) ORED(o12) ORED(o13) ORED(o14) ORED(o15)
    ORED(l_run)
    #undef ORED
    if (c16 == 0) {
        float* sp = &s_part[w][0];
        sp[g16 * 8 + 0] = o00;  sp[g16 * 8 + 1] = o01;
        sp[g16 * 8 + 2] = o02;  sp[g16 * 8 + 3] = o03;
        sp[g16 * 8 + 4] = o04;  sp[g16 * 8 + 5] = o05;
        sp[g16 * 8 + 6] = o06;  sp[g16 * 8 + 7] = o07;
        sp[32 + g16 * 8 + 0] = o08;  sp[32 + g16 * 8 + 1] = o09;
        sp[32 + g16 * 8 + 2] = o10;  sp[32 + g16 * 8 + 3] = o11;
        sp[32 + g16 * 8 + 4] = o12;  sp[32 + g16 * 8 + 5] = o13;
        sp[32 + g16 * 8 + 6] = o14;  sp[32 + g16 * 8 + 7] = o15;
    }
    if (lane == 0) s_l[w] = l_run;
    __syncthreads();

    // merge: batch slot k uses waves 2k, 2k+1 (pure addition — fixed-m)
    if ((tid & 127) < D_) {
        int k  = tid >> 7;                 // batch slot 0/1
        int d  = tid & 63;
        int bo = blockIdx.x * 2 + k;
        float ot = s_part[2 * k][d] + s_part[2 * k + 1][d];
        float lt = s_l[2 * k] + s_l[2 * k + 1];
        out[bo * D_ + d] = ot * __builtin_amdgcn_rcpf(lt);
    }
}

extern "C" void kernel_launch(void* const* d_in, const int* in_sizes, int n_in,
                              void* d_out, int out_size, void* d_ws, size_t ws_size,
                              hipStream_t stream)
{
    const float* query = (const float*)d_in[0];
    const float* key   = (const float*)d_in[1];
    const int*   mask  = (const int*)  d_in[2];
    const float* W1    = (const float*)d_in[3];
    const float* b1    = (const float*)d_in[4];
    const float* W2    = (const float*)d_in[5];
    const float* b2    = (const float*)d_in[6];
    const float* W3    = (const float*)d_in[7];
    const float* b3    = (const float*)d_in[8];
    float* out = (float*)d_out;

    prep_kernel<<<8, 256, 0, stream>>>(W1, W2, d_ws);
    attn_din21<<<B_ / 2, 256, 0, stream>>>(query, key, mask, b1, b2, W3, b3, d_ws, out);
}

// Round 22
// 42.723 us; speedup vs baseline: 1.1960x; 1.1960x over previous
//
#include <hip/hip_runtime.h>
#include <math.h>

#define B_  2048
#define T_  200
#define D_  64
#define H1_ 80
#define H2_ 40

#define WSTR 104   // ws W2T row stride (bf16)
#define NLOG2E (-1.4426950408889634f)
#define LOG2E  (1.4426950408889634f)

// d_ws layout (bytes):
#define WS_A    0        // A[h][f]  bf16 [80][64]   (pre-scaled by -log2e)
#define WS_C    10240    // C[h][f]  bf16 [80][64]   (pre-scaled by -log2e)
#define WS_W2T  20480    // W2Tp[g][h] bf16 [48][104] (pre-scaled by -log2e)
#define WS_ACT  30464    // W1acT[h][f] f32 [80][64]  (unscaled)
#define WS_PERM 51200    // int perm[2048]

typedef __bf16 bf16x8 __attribute__((ext_vector_type(8)));
typedef float  f32x4  __attribute__((ext_vector_type(4)));

__device__ __forceinline__ float sigmoid2_(float y) {   // y = -log2e*x
    return __builtin_amdgcn_rcpf(1.0f + __builtin_amdgcn_exp2f(y));
}
__device__ __forceinline__ unsigned pk2_(float a, float b) {
    __bf16 x = (__bf16)a, y = (__bf16)b;
    unsigned short ux = __builtin_bit_cast(unsigned short, x);
    unsigned short uy = __builtin_bit_cast(unsigned short, y);
    return (unsigned)ux | ((unsigned)uy << 16);
}

// ---------- prep: block-invariant weight transforms (exp2-folded) ----------
__global__ __launch_bounds__(256)
void prep_kernel(const float* __restrict__ W1, const float* __restrict__ W2,
                 void* __restrict__ ws)
{
    __bf16* A    = (__bf16*)((char*)ws + WS_A);
    __bf16* C    = (__bf16*)((char*)ws + WS_C);
    __bf16* W2Tp = (__bf16*)((char*)ws + WS_W2T);
    float*  acT  = (float*)((char*)ws + WS_ACT);
    const int e0 = blockIdx.x * 256 + threadIdx.x;

    for (int e = e0; e < H1_ * D_; e += 2048) {
        int h = e >> 6, f = e & 63;
        float wb = W1[(64  + f) * H1_ + h];
        float wc = W1[(128 + f) * H1_ + h];
        float wd = W1[(192 + f) * H1_ + h];
        float wa = W1[f * H1_ + h];
        A[e]   = (__bf16)(NLOG2E * (wb - wc));
        C[e]   = (__bf16)(NLOG2E * wd);
        acT[e] = wa + wc;
    }
    for (int e = e0; e < 48 * WSTR; e += 2048) {
        int g = e / WSTR, h = e - g * WSTR;
        W2Tp[e] = (g < H2_ && h < H1_) ? (__bf16)(NLOG2E * W2[h * H2_ + g]) : (__bf16)0.0f;
    }
}

// ---------- sort: counting-sort batches by mask desc; pair rank r with 2047-r ----------
__global__ __launch_bounds__(256)
void sort_kernel(const int* __restrict__ mask, void* __restrict__ ws)
{
    int* perm = (int*)((char*)ws + WS_PERM);
    __shared__ int hist[201];
    __shared__ int pfx[201];
    __shared__ int S[B_];          // 8 KB
    const int tid = threadIdx.x;

    for (int i = tid; i <= 200; i += 256) hist[i] = 0;
    __syncthreads();
    for (int b = tid; b < B_; b += 256) atomicAdd(&hist[mask[b]], 1);
    __syncthreads();
    if (tid == 0) {
        int acc = 0;
        for (int v = 200; v >= 1; --v) { pfx[v] = acc; acc += hist[v]; }
    }
    __syncthreads();
    for (int i = tid; i <= 200; i += 256) hist[i] = 0;
    __syncthreads();
    for (int b = tid; b < B_; b += 256) {
        int v = mask[b];
        int pos = pfx[v] + atomicAdd(&hist[v], 1);
        S[pos] = b;                // descending mv order
    }
    __syncthreads();
    // block blk (8 waves): w<4 -> large ranks blk*4+w ; w>=4 -> small ranks 2047-blk*4-(w-4)
    for (int i = tid; i < B_; i += 256) {
        int blk = i >> 3, w = i & 7;
        perm[i] = (w < 4) ? S[blk * 4 + w] : S[2047 - blk * 4 - (w - 4)];
    }
}

// ---------- main: 8 waves/block, one batch per wave via balanced perm ----------
__global__ __launch_bounds__(512, 2)
void attn_din22(const float* __restrict__ query,
                const float* __restrict__ key,
                const int*   __restrict__ mask,
                const float* __restrict__ b1,
                const float* __restrict__ b2,
                const float* __restrict__ W3,
                const float* __restrict__ b3,
                const void*  __restrict__ ws,
                float* __restrict__ out)
{
    __shared__ __align__(16) float s_q[8][D_];
    __shared__ float s_base[8][H1_];
    __shared__ float s_part[8][D_];
    // ~6.5 KB

    const int tid  = threadIdx.x;
    const int lane = tid & 63;
    const int w    = tid >> 6;          // wave 0..7
    const int c16  = lane & 15;
    const int g16  = lane >> 4;

    const int* perm = (const int*)((const char*)ws + WS_PERM);
    const int b = perm[blockIdx.x * 8 + w];

    const int   mv     = mask[b];
    const int   npairs = (mv + 31) >> 5;
    const float b3s    = b3[0] * 0.125f * LOG2E;
    const float* kb = key + (size_t)b * T_ * D_;

    const __bf16* wsA   = (const __bf16*)((const char*)ws + WS_A);
    const __bf16* wsC   = (const __bf16*)((const char*)ws + WS_C);
    const __bf16* wsW2T = (const __bf16*)((const char*)ws + WS_W2T);
    const float*  wsacT = (const float*) ((const char*)ws + WS_ACT);

    // ---- q + pair-0 key loads issued early ----
    float qv = query[b * D_ + lane];
    float4 uA0, uA1, uA2, uA3, uB0, uB1, uB2, uB3;
    {
        const float* krA = kb + (size_t)c16 * D_ + g16 * 8;
        const float* krB = kb + (size_t)(16 + c16) * D_ + g16 * 8;
        uA0 = *(const float4*)(krA);      uA1 = *(const float4*)(krA + 4);
        uA2 = *(const float4*)(krA + 32); uA3 = *(const float4*)(krA + 36);
        uB0 = *(const float4*)(krB);      uB1 = *(const float4*)(krB + 4);
        uB2 = *(const float4*)(krB + 32); uB3 = *(const float4*)(krB + 36);
    }
    s_q[w][lane] = qv;

    // ---- W2T A-fragments (pre-scaled by -log2e) ----
    bf16x8 bw[3][3];
    #pragma unroll
    for (int nt = 0; nt < 3; ++nt)
        #pragma unroll
        for (int ks = 0; ks < 3; ++ks)
            bw[nt][ks] = *(const bf16x8*)&wsW2T[(nt * 16 + c16) * WSTR + ks * 32 + g16 * 8];

    // ---- per-lane bias/weight rows ----
    float b2c[3][4], w3c[3][4];
    #pragma unroll
    for (int nt = 0; nt < 3; ++nt)
        #pragma unroll
        for (int r = 0; r < 4; ++r) {
            int g = nt * 16 + g16 * 4 + r;
            b2c[nt][r] = (g < H2_) ? b2[g] * NLOG2E : 0.0f;
            w3c[nt][r] = (g < H2_) ? W3[g] * 0.125f * LOG2E : 0.0f;
        }

    // ---- base[h] ----
    {
        float a0 = b1[lane], a1 = 0.0f, a2 = 0.0f, a3 = 0.0f;
        const f32x4* row = (const f32x4*)&wsacT[lane * D_];
        #pragma unroll
        for (int f4 = 0; f4 < 16; ++f4) {
            f32x4 v  = row[f4];
            f32x4 q4 = *(const f32x4*)&s_q[w][f4 * 4];
            a0 = fmaf(q4[0], v[0], a0);
            a1 = fmaf(q4[1], v[1], a1);
            a2 = fmaf(q4[2], v[2], a2);
            a3 = fmaf(q4[3], v[3], a3);
        }
        s_base[w][lane] = (a0 + a1) + (a2 + a3);
    }
    if (lane < 16) {
        int h = 64 + lane;
        float a0 = b1[h], a1 = 0.0f, a2 = 0.0f, a3 = 0.0f;
        const f32x4* row = (const f32x4*)&wsacT[h * D_];
        #pragma unroll
        for (int f4 = 0; f4 < 16; ++f4) {
            f32x4 v  = row[f4];
            f32x4 q4 = *(const f32x4*)&s_q[w][f4 * 4];
            a0 = fmaf(q4[0], v[0], a0);
            a1 = fmaf(q4[1], v[1], a1);
            a2 = fmaf(q4[2], v[2], a2);
            a3 = fmaf(q4[3], v[3], a3);
        }
        s_base[w][h] = (a0 + a1) + (a2 + a3);
    }

    // ---- V A-fragments (pre-scaled) ----
    bf16x8 bv[5][2];
    #pragma unroll
    for (int mt = 0; mt < 5; ++mt)
        #pragma unroll
        for (int ks = 0; ks < 2; ++ks) {
            int off = (mt * 16 + c16) * D_ + ks * 32 + g16 * 8;
            bf16x8 a8 = *(const bf16x8*)&wsA[off];
            bf16x8 c8 = *(const bf16x8*)&wsC[off];
            f32x4 q0 = *(const f32x4*)&s_q[w][ks * 32 + g16 * 8];
            f32x4 q1 = *(const f32x4*)&s_q[w][ks * 32 + g16 * 8 + 4];
            bf16x8 v8;
            v8[0] = (__bf16)((float)a8[0] + q0[0] * (float)c8[0]);
            v8[1] = (__bf16)((float)a8[1] + q0[1] * (float)c8[1]);
            v8[2] = (__bf16)((float)a8[2] + q0[2] * (float)c8[2]);
            v8[3] = (__bf16)((float)a8[3] + q0[3] * (float)c8[3]);
            v8[4] = (__bf16)((float)a8[4] + q1[0] * (float)c8[4]);
            v8[5] = (__bf16)((float)a8[5] + q1[1] * (float)c8[5]);
            v8[6] = (__bf16)((float)a8[6] + q1[2] * (float)c8[6]);
            v8[7] = (__bf16)((float)a8[7] + q1[3] * (float)c8[7]);
            bv[mt][ks] = v8;
        }

    // ---- per-lane base rows, scaled by -log2e ----
    float base_c[5][4];
    #pragma unroll
    for (int mt = 0; mt < 5; ++mt)
        #pragma unroll
        for (int r = 0; r < 4; ++r)
            base_c[mt][r] = s_base[w][16 * mt + g16 * 4 + r] * NLOG2E;

    // ---- shfl-assembly constants ----
    const int  L0 = ((g16 & 1) << 5) + c16;
    const int  L1 = L0 + 16;
    const bool hi = (g16 >= 2);

    // ---- accumulators ----
    float o00,o01,o02,o03,o04,o05,o06,o07,o08,o09,o10,o11,o12,o13,o14,o15;
    o00=o01=o02=o03=o04=o05=o06=o07=o08=o09=o10=o11=o12=o13=o14=o15=0.0f;
    float l_run = 0.0f;

    // ---------------- main loop ----------------
    for (int pp = 0; pp < npairs; ++pp) {
        bf16x8 afA0, afA1, afB0, afB1;
        afA0[0]=(__bf16)uA0.x; afA0[1]=(__bf16)uA0.y; afA0[2]=(__bf16)uA0.z; afA0[3]=(__bf16)uA0.w;
        afA0[4]=(__bf16)uA1.x; afA0[5]=(__bf16)uA1.y; afA0[6]=(__bf16)uA1.z; afA0[7]=(__bf16)uA1.w;
        afA1[0]=(__bf16)uA2.x; afA1[1]=(__bf16)uA2.y; afA1[2]=(__bf16)uA2.z; afA1[3]=(__bf16)uA2.w;
        afA1[4]=(__bf16)uA3.x; afA1[5]=(__bf16)uA3.y; afA1[6]=(__bf16)uA3.z; afA1[7]=(__bf16)uA3.w;
        afB0[0]=(__bf16)uB0.x; afB0[1]=(__bf16)uB0.y; afB0[2]=(__bf16)uB0.z; afB0[3]=(__bf16)uB0.w;
        afB0[4]=(__bf16)uB1.x; afB0[5]=(__bf16)uB1.y; afB0[6]=(__bf16)uB1.z; afB0[7]=(__bf16)uB1.w;
        afB1[0]=(__bf16)uB2.x; afB1[1]=(__bf16)uB2.y; afB1[2]=(__bf16)uB2.z; afB1[3]=(__bf16)uB2.w;
        afB1[4]=(__bf16)uB3.x; afB1[5]=(__bf16)uB3.y; afB1[6]=(__bf16)uB3.z; afB1[7]=(__bf16)uB3.w;

        if (pp + 1 < npairs) {
            int trA = (pp + 1) * 32 + c16;
            int trB = trA + 16;
            const float* krA = kb + (size_t)((trA < T_) ? trA : (T_ - 1)) * D_ + g16 * 8;
            const float* krB = kb + (size_t)((trB < T_) ? trB : (T_ - 1)) * D_ + g16 * 8;
            uA0 = *(const float4*)(krA);      uA1 = *(const float4*)(krA + 4);
            uA2 = *(const float4*)(krA + 32); uA3 = *(const float4*)(krA + 36);
            uB0 = *(const float4*)(krB);      uB1 = *(const float4*)(krB + 4);
            uB2 = *(const float4*)(krB + 32); uB3 = *(const float4*)(krB + 36);
        }

        // layer 1 swapped; sigmoid via exp2 -> packed bf16
        unsigned pkA[5][2], pkB[5][2];
        __builtin_amdgcn_s_setprio(1);
        #pragma unroll
        for (int mt = 0; mt < 5; ++mt) {
            f32x4 cA = { base_c[mt][0], base_c[mt][1], base_c[mt][2], base_c[mt][3] };
            cA = __builtin_amdgcn_mfma_f32_16x16x32_bf16(bv[mt][0], afA0, cA, 0, 0, 0);
            cA = __builtin_amdgcn_mfma_f32_16x16x32_bf16(bv[mt][1], afA1, cA, 0, 0, 0);
            f32x4 cB = { base_c[mt][0], base_c[mt][1], base_c[mt][2], base_c[mt][3] };
            cB = __builtin_amdgcn_mfma_f32_16x16x32_bf16(bv[mt][0], afB0, cB, 0, 0, 0);
            cB = __builtin_amdgcn_mfma_f32_16x16x32_bf16(bv[mt][1], afB1, cB, 0, 0, 0);
            pkA[mt][0] = pk2_(sigmoid2_(cA[0]), sigmoid2_(cA[1]));
            pkA[mt][1] = pk2_(sigmoid2_(cA[2]), sigmoid2_(cA[3]));
            pkB[mt][0] = pk2_(sigmoid2_(cB[0]), sigmoid2_(cB[1]));
            pkB[mt][1] = pk2_(sigmoid2_(cB[2]), sigmoid2_(cB[3]));
        }
        __builtin_amdgcn_s_setprio(0);

        // B-frag assembly + layer 2 + layer 3, per sub-tile
        float sA, sB;
        #pragma unroll
        for (int sub = 0; sub < 2; ++sub) {
            unsigned w00,w01,w02,w03, w10,w11,w12,w13, w20,w21,w22,w23;
            {
                #define PKX(m,i) (sub ? pkB[m][i] : pkA[m][i])
                unsigned a,bq;
                a = __shfl(PKX(0,0), L0); bq = __shfl(PKX(1,0), L0); w00 = hi ? bq : a;
                a = __shfl(PKX(0,1), L0); bq = __shfl(PKX(1,1), L0); w01 = hi ? bq : a;
                a = __shfl(PKX(0,0), L1); bq = __shfl(PKX(1,0), L1); w02 = hi ? bq : a;
                a = __shfl(PKX(0,1), L1); bq = __shfl(PKX(1,1), L1); w03 = hi ? bq : a;
                a = __shfl(PKX(2,0), L0); bq = __shfl(PKX(3,0), L0); w10 = hi ? bq : a;
                a = __shfl(PKX(2,1), L0); bq = __shfl(PKX(3,1), L0); w11 = hi ? bq : a;
                a = __shfl(PKX(2,0), L1); bq = __shfl(PKX(3,0), L1); w12 = hi ? bq : a;
                a = __shfl(PKX(2,1), L1); bq = __shfl(PKX(3,1), L1); w13 = hi ? bq : a;
                a = __shfl(PKX(4,0), L0);                            w20 = hi ? 0u : a;
                a = __shfl(PKX(4,1), L0);                            w21 = hi ? 0u : a;
                a = __shfl(PKX(4,0), L1);                            w22 = hi ? 0u : a;
                a = __shfl(PKX(4,1), L1);                            w23 = hi ? 0u : a;
                #undef PKX
            }
            union { unsigned u[4]; bf16x8 v; } cv0, cv1, cv2;
            cv0.u[0]=w00; cv0.u[1]=w01; cv0.u[2]=w02; cv0.u[3]=w03;
            cv1.u[0]=w10; cv1.u[1]=w11; cv1.u[2]=w12; cv1.u[3]=w13;
            cv2.u[0]=w20; cv2.u[1]=w21; cv2.u[2]=w22; cv2.u[3]=w23;

            float p0 = 0.0f, p1 = 0.0f, p2 = 0.0f, p3 = 0.0f;
            __builtin_amdgcn_s_setprio(1);
            #pragma unroll
            for (int nt2 = 0; nt2 < 3; ++nt2) {
                f32x4 c = { b2c[nt2][0], b2c[nt2][1], b2c[nt2][2], b2c[nt2][3] };
                c = __builtin_amdgcn_mfma_f32_16x16x32_bf16(bw[nt2][0], cv0.v, c, 0, 0, 0);
                c = __builtin_amdgcn_mfma_f32_16x16x32_bf16(bw[nt2][1], cv1.v, c, 0, 0, 0);
                c = __builtin_amdgcn_mfma_f32_16x16x32_bf16(bw[nt2][2], cv2.v, c, 0, 0, 0);
                p0 = fmaf(sigmoid2_(c[0]), w3c[nt2][0], p0);
                p1 = fmaf(sigmoid2_(c[1]), w3c[nt2][1], p1);
                p2 = fmaf(sigmoid2_(c[2]), w3c[nt2][2], p2);
                p3 = fmaf(sigmoid2_(c[3]), w3c[nt2][3], p3);
            }
            __builtin_amdgcn_s_setprio(0);
            float partial = (p0 + p1) + (p2 + p3);
            partial += __shfl_xor(partial, 16);
            partial += __shfl_xor(partial, 32);
            float sc = partial + b3s;
            if (sub == 0) sA = sc; else sB = sc;
        }

        // fixed-m softmax in exp2 domain
        const int tb = pp * 32;
        float pA = (tb + c16 < mv)      ? __builtin_amdgcn_exp2f(sA) : 0.0f;
        float pB = (tb + 16 + c16 < mv) ? __builtin_amdgcn_exp2f(sB) : 0.0f;
        l_run += pA + pB;

        o00 = fmaf(pB, (float)afB0[0], fmaf(pA, (float)afA0[0], o00));
        o01 = fmaf(pB, (float)afB0[1], fmaf(pA, (float)afA0[1], o01));
        o02 = fmaf(pB, (float)afB0[2], fmaf(pA, (float)afA0[2], o02));
        o03 = fmaf(pB, (float)afB0[3], fmaf(pA, (float)afA0[3], o03));
        o04 = fmaf(pB, (float)afB0[4], fmaf(pA, (float)afA0[4], o04));
        o05 = fmaf(pB, (float)afB0[5], fmaf(pA, (float)afA0[5], o05));
        o06 = fmaf(pB, (float)afB0[6], fmaf(pA, (float)afA0[6], o06));
        o07 = fmaf(pB, (float)afB0[7], fmaf(pA, (float)afA0[7], o07));
        o08 = fmaf(pB, (float)afB1[0], fmaf(pA, (float)afA1[0], o08));
        o09 = fmaf(pB, (float)afB1[1], fmaf(pA, (float)afA1[1], o09));
        o10 = fmaf(pB, (float)afB1[2], fmaf(pA, (float)afA1[2], o10));
        o11 = fmaf(pB, (float)afB1[3], fmaf(pA, (float)afA1[3], o11));
        o12 = fmaf(pB, (float)afB1[4], fmaf(pA, (float)afA1[4], o12));
        o13 = fmaf(pB, (float)afB1[5], fmaf(pA, (float)afA1[5], o13));
        o14 = fmaf(pB, (float)afB1[6], fmaf(pA, (float)afA1[6], o14));
        o15 = fmaf(pB, (float)afB1[7], fmaf(pA, (float)afA1[7], o15));
    }

    // ---------------- finalize: reduce o and l over c16 lanes, normalize, store ----------------
    #define ORED(X) X += __shfl_xor(X,1); X += __shfl_xor(X,2); X += __shfl_xor(X,4); X += __shfl_xor(X,8);
    ORED(o00) ORED(o01) ORED(o02) ORED(o03) ORED(o04) ORED(o05) ORED(o06) ORED(o07)
    ORED(o08) ORED(o09) ORED(o10) ORED(o11) ORED(o12) ORED(o13) ORED(o14) ORED(o15)
    ORED(l_run)
    #undef ORED
    float inv_total = __builtin_amdgcn_rcpf(l_run);
    if (c16 == 0) {
        float* sp = &s_part[w][0];
        sp[g16 * 8 + 0] = o00;  sp[g16 * 8 + 1] = o01;
        sp[g16 * 8 + 2] = o02;  sp[g16 * 8 + 3] = o03;
        sp[g16 * 8 + 4] = o04;  sp[g16 * 8 + 5] = o05;
        sp[g16 * 8 + 6] = o06;  sp[g16 * 8 + 7] = o07;
        sp[32 + g16 * 8 + 0] = o08;  sp[32 + g16 * 8 + 1] = o09;
        sp[32 + g16 * 8 + 2] = o10;  sp[32 + g16 * 8 + 3] = o11;
        sp[32 + g16 * 8 + 4] = o12;  sp[32 + g16 * 8 + 5] = o13;
        sp[32 + g16 * 8 + 6] = o14;  sp[32 + g16 * 8 + 7] = o15;
    }
    asm volatile("s_waitcnt lgkmcnt(0)" ::: "memory");
    out[b * D_ + lane] = s_part[w][lane] * inv_total;
}

extern "C" void kernel_launch(void* const* d_in, const int* in_sizes, int n_in,
                              void* d_out, int out_size, void* d_ws, size_t ws_size,
                              hipStream_t stream)
{
    const float* query = (const float*)d_in[0];
    const float* key   = (const float*)d_in[1];
    const int*   mask  = (const int*)  d_in[2];
    const float* W1    = (const float*)d_in[3];
    const float* b1    = (const float*)d_in[4];
    const float* W2    = (const float*)d_in[5];
    const float* b2    = (const float*)d_in[6];
    const float* W3    = (const float*)d_in[7];
    const float* b3    = (const float*)d_in[8];
    float* out = (float*)d_out;

    prep_kernel<<<8, 256, 0, stream>>>(W1, W2, d_ws);
    sort_kernel<<<1, 256, 0, stream>>>(mask, d_ws);
    attn_din22<<<B_ / 8, 512, 0, stream>>>(query, key, mask, b1, b2, W3, b3, d_ws, out);
}